// Round 2
// baseline (629.488 us; speedup 1.0000x reference)
//
#include <hip/hip_runtime.h>

// Problem constants (from reference): B=8192 rows, ITEM_NUM=10000 cols.
#define ROWS 8192
#define COLS 10000
#define COLS4 (COLS / 4)     // 2500 float4 per row; 40000 B row stride (16B-aligned)
#define BLK 256
#define WAVES_PER_BLK (BLK / 64)
#define MAIN_ITERS 19        // uniform double-steps: covers float4 idx 0..2431 (19*128)

// Native clang vector type (HIP float4 is a class; this maps to 4 VGPRs).
typedef float vf4 __attribute__((ext_vector_type(4)));

__device__ __forceinline__ float dot4(vf4 a, vf4 b) {
    return a.x * b.x + a.y * b.y + a.z * b.z + a.w * b.w;
}

// One WAVE per row (4 rows per block). W is staged once per block into LDS
// (40 KB) so the main loop's VMEM pipe issues ONLY contiguous stream loads;
// W comes from the independent LDS pipe (ds_read_b128, conflict-free).
// Plain cached loads for the streams (nt dropped: W no longer needs L2, and
// the 6.3 TB/s copy ceiling was measured with cached float4 loads).
__global__ __launch_bounds__(BLK) void qloss_rows_kernel(
    const float* __restrict__ hidden,
    const float* __restrict__ target,
    const float* __restrict__ rewards,
    const float* __restrict__ discount,   // 1-element
    const unsigned char* __restrict__ is_done,
    const float* __restrict__ W,          // [10000]
    const float* __restrict__ bias,       // 1-element
    float* __restrict__ partial)          // [ROWS]
{
    __shared__ vf4 wlds[COLS4];           // 40000 B, 16B-aligned

    // Cooperative one-time W stage: 2500 float4 by 256 threads (~10 iters).
    for (int i = threadIdx.x; i < COLS4; i += BLK)
        wlds[i] = ((const vf4*)W)[i];
    __syncthreads();

    const int lane = threadIdx.x & 63;
    const int wid  = threadIdx.x >> 6;
    const int row  = blockIdx.x * WAVES_PER_BLK + wid;

    const vf4* __restrict__ h4 = (const vf4*)(hidden + (size_t)row * COLS);
    const vf4* __restrict__ t4 = (const vf4*)(target + (size_t)row * COLS);

    // 2x-unrolled body: 4 independent accumulators, 4 streaming loads +
    // 2 LDS reads per step. Trip count is lane-uniform (no exec masking).
    float ah0 = 0.f, ah1 = 0.f, at0 = 0.f, at1 = 0.f;
    int j = lane;
    #pragma unroll 2
    for (int k = 0; k < MAIN_ITERS; ++k, j += 128) {
        vf4 h0 = h4[j];
        vf4 h1 = h4[j + 64];
        vf4 t0 = t4[j];
        vf4 t1 = t4[j + 64];
        vf4 w0 = wlds[j];
        vf4 w1 = wlds[j + 64];
        ah0 += dot4(h0, w0);
        ah1 += dot4(h1, w1);
        at0 += dot4(t0, w0);
        at1 += dot4(t1, w1);
    }
    // j == lane + 2432 here. Full-wave single step covers 2432..2495.
    {
        vf4 h0 = h4[j];
        vf4 t0 = t4[j];
        vf4 w0 = wlds[j];
        ah0 += dot4(h0, w0);
        at0 += dot4(t0, w0);
    }
    // Last 4 float4 (2496..2499): lanes 0..3 only.
    if (lane < 4) {
        int j2 = j + 64;
        vf4 h1 = h4[j2];
        vf4 t1 = t4[j2];
        vf4 w1 = wlds[j2];
        ah1 += dot4(h1, w1);
        at1 += dot4(t1, w1);
    }

    float ah = ah0 + ah1;
    float at = at0 + at1;

    // Wave (64-lane) reduction
    #pragma unroll
    for (int off = 32; off > 0; off >>= 1) {
        ah += __shfl_down(ah, off, 64);
        at += __shfl_down(at, off, 64);
    }

    if (lane == 0) {
        float b  = bias[0];
        float q  = fmaxf(ah + b, 0.f);
        float nq = fmaxf(at + b, 0.f);
        float loss = fabsf(rewards[row] + discount[0] * nq - q);
        partial[row] = is_done[row] ? 0.f : loss;
    }
}

// Single-block final reduction: sum 8192 partials, divide by B, write d_out[0].
// Must WRITE (not accumulate) since d_out is poisoned 0xAA before timed runs.
__global__ __launch_bounds__(BLK) void qloss_reduce_kernel(
    const float* __restrict__ partial,
    float* __restrict__ out)
{
    float s = 0.f;
    for (int i = threadIdx.x; i < ROWS; i += BLK) s += partial[i];

    #pragma unroll
    for (int off = 32; off > 0; off >>= 1) s += __shfl_down(s, off, 64);

    __shared__ float sm[BLK / 64];
    const int lane = threadIdx.x & 63;
    const int wid  = threadIdx.x >> 6;
    if (lane == 0) sm[wid] = s;
    __syncthreads();

    if (threadIdx.x == 0) {
        float total = sm[0] + sm[1] + sm[2] + sm[3];
        out[0] = total / (float)ROWS;
    }
}

extern "C" void kernel_launch(void* const* d_in, const int* in_sizes, int n_in,
                              void* d_out, int out_size, void* d_ws, size_t ws_size,
                              hipStream_t stream) {
    // setup_inputs() order:
    // 0: hidden_states [8192,10000] f32
    // 1: actions       [8192]       int32  (unused by reference)
    // 2: rewards       [8192]       f32
    // 3: discount      [1]          f32
    // 4: targetQs_s    [8192,10000] f32
    // 5: is_done       [8192]       bool (all false; read as bytes)
    // 6: W             [1,10000]    f32
    // 7: b             [1]          f32
    const float*         hidden   = (const float*)d_in[0];
    const float*         rewards  = (const float*)d_in[2];
    const float*         discount = (const float*)d_in[3];
    const float*         target   = (const float*)d_in[4];
    const unsigned char* is_done  = (const unsigned char*)d_in[5];
    const float*         W        = (const float*)d_in[6];
    const float*         b        = (const float*)d_in[7];
    float*               out      = (float*)d_out;
    float*               partial  = (float*)d_ws;   // needs ROWS*4 = 32 KB

    qloss_rows_kernel<<<ROWS / WAVES_PER_BLK, BLK, 0, stream>>>(
        hidden, target, rewards, discount, is_done, W, b, partial);
    qloss_reduce_kernel<<<1, BLK, 0, stream>>>(partial, out);
}

// Round 3
// 587.959 us; speedup vs baseline: 1.0706x; 1.0706x over previous
//
#include <hip/hip_runtime.h>

// Problem constants (from reference): B=8192 rows, ITEM_NUM=10000 cols.
#define ROWS 8192
#define COLS 10000
#define COLS4 (COLS / 4)     // 2500 float4 per row; 40000 B row stride (16B-aligned)
#define BLK 256

// Native clang vector type (HIP float4 is a class; this maps to 4 VGPRs;
// accepted by __builtin_nontemporal_load).
typedef float vf4 __attribute__((ext_vector_type(4)));

__device__ __forceinline__ float dot4(vf4 a, vf4 b) {
    return a.x * b.x + a.y * b.y + a.z * b.z + a.w * b.w;
}

// One BLOCK (256 threads) per row. The block streams h[row] and t[row] with
// block-stride coalesced loads (4 KB per round), so chip-wide there are
// ~4x fewer, 4x coarser concurrent HBM streams than wave-per-row — DRAM
// page-locality is the lever (copy probe sweeps lockstep and hits 6.3 TB/s).
// h/t use nontemporal loads (single-use; keep L2 for W). W is read plain
// from global: 40 KB, L2-resident after first touch, shared by h and t dots.
__global__ __launch_bounds__(BLK) void qloss_rows_kernel(
    const float* __restrict__ hidden,
    const float* __restrict__ target,
    const float* __restrict__ rewards,
    const float* __restrict__ discount,   // 1-element
    const unsigned char* __restrict__ is_done,
    const float* __restrict__ W,          // [10000]
    const float* __restrict__ bias,       // 1-element
    float* __restrict__ partial)          // [ROWS]
{
    const int tid  = threadIdx.x;
    const int lane = tid & 63;
    const int wid  = tid >> 6;
    const int row  = blockIdx.x;

    const vf4* __restrict__ h4 = (const vf4*)(hidden + (size_t)row * COLS);
    const vf4* __restrict__ t4 = (const vf4*)(target + (size_t)row * COLS);
    const vf4* __restrict__ w4 = (const vf4*)W;

    // COLS4 = 2500 = 8*256 (4 double-rounds) + 256 (1 single round) + 196 tail.
    float ah0 = 0.f, ah1 = 0.f, at0 = 0.f, at1 = 0.f;
    int j = tid;
    for (int k = 0; k < 4; ++k, j += 512) {
        vf4 w0 = w4[j];
        vf4 w1 = w4[j + 256];
        vf4 h0 = __builtin_nontemporal_load(&h4[j]);
        vf4 h1 = __builtin_nontemporal_load(&h4[j + 256]);
        vf4 t0 = __builtin_nontemporal_load(&t4[j]);
        vf4 t1 = __builtin_nontemporal_load(&t4[j + 256]);
        ah0 += dot4(h0, w0);
        ah1 += dot4(h1, w1);
        at0 += dot4(t0, w0);
        at1 += dot4(t1, w1);
    }
    // j == tid + 2048 here: full round covers 2048..2303.
    {
        vf4 w0 = w4[j];
        vf4 h0 = __builtin_nontemporal_load(&h4[j]);
        vf4 t0 = __builtin_nontemporal_load(&t4[j]);
        ah0 += dot4(h0, w0);
        at0 += dot4(t0, w0);
    }
    // Tail: float4 idx 2304..2499 (196 elements), threads 0..195.
    if (tid < COLS4 - 2304) {
        int j2 = 2304 + tid;
        vf4 w1 = w4[j2];
        vf4 h1 = __builtin_nontemporal_load(&h4[j2]);
        vf4 t1 = __builtin_nontemporal_load(&t4[j2]);
        ah1 += dot4(h1, w1);
        at1 += dot4(t1, w1);
    }

    float ah = ah0 + ah1;
    float at = at0 + at1;

    // Wave (64-lane) reduction
    #pragma unroll
    for (int off = 32; off > 0; off >>= 1) {
        ah += __shfl_down(ah, off, 64);
        at += __shfl_down(at, off, 64);
    }

    // Cross-wave combine (4 waves) + epilogue.
    __shared__ float smh[BLK / 64];
    __shared__ float smt[BLK / 64];
    if (lane == 0) { smh[wid] = ah; smt[wid] = at; }
    __syncthreads();

    if (tid == 0) {
        float AH = smh[0] + smh[1] + smh[2] + smh[3];
        float AT = smt[0] + smt[1] + smt[2] + smt[3];
        float b  = bias[0];
        float q  = fmaxf(AH + b, 0.f);
        float nq = fmaxf(AT + b, 0.f);
        float loss = fabsf(rewards[row] + discount[0] * nq - q);
        partial[row] = is_done[row] ? 0.f : loss;
    }
}

// Single-block final reduction: sum 8192 partials, divide by B, write d_out[0].
// Must WRITE (not accumulate) since d_out is poisoned 0xAA before timed runs.
__global__ __launch_bounds__(BLK) void qloss_reduce_kernel(
    const float* __restrict__ partial,
    float* __restrict__ out)
{
    float s = 0.f;
    for (int i = threadIdx.x; i < ROWS; i += BLK) s += partial[i];

    #pragma unroll
    for (int off = 32; off > 0; off >>= 1) s += __shfl_down(s, off, 64);

    __shared__ float sm[BLK / 64];
    const int lane = threadIdx.x & 63;
    const int wid  = threadIdx.x >> 6;
    if (lane == 0) sm[wid] = s;
    __syncthreads();

    if (threadIdx.x == 0) {
        float total = sm[0] + sm[1] + sm[2] + sm[3];
        out[0] = total / (float)ROWS;
    }
}

extern "C" void kernel_launch(void* const* d_in, const int* in_sizes, int n_in,
                              void* d_out, int out_size, void* d_ws, size_t ws_size,
                              hipStream_t stream) {
    // setup_inputs() order:
    // 0: hidden_states [8192,10000] f32
    // 1: actions       [8192]       int32  (unused by reference)
    // 2: rewards       [8192]       f32
    // 3: discount      [1]          f32
    // 4: targetQs_s    [8192,10000] f32
    // 5: is_done       [8192]       bool (all false; read as bytes)
    // 6: W             [1,10000]    f32
    // 7: b             [1]          f32
    const float*         hidden   = (const float*)d_in[0];
    const float*         rewards  = (const float*)d_in[2];
    const float*         discount = (const float*)d_in[3];
    const float*         target   = (const float*)d_in[4];
    const unsigned char* is_done  = (const unsigned char*)d_in[5];
    const float*         W        = (const float*)d_in[6];
    const float*         b        = (const float*)d_in[7];
    float*               out      = (float*)d_out;
    float*               partial  = (float*)d_ws;   // needs ROWS*4 = 32 KB

    qloss_rows_kernel<<<ROWS, BLK, 0, stream>>>(
        hidden, target, rewards, discount, is_done, W, b, partial);
    qloss_reduce_kernel<<<1, BLK, 0, stream>>>(partial, out);
}